// Round 8
// baseline (1125.342 us; speedup 1.0000x reference)
//
#include <hip/hip_runtime.h>
#include <math.h>

// B=32, S=2048, D=512, R=4, H=32. Tokens = 65536. Tile = 64 tokens.
#define NTOK 65536
#define TOK 64
#define NTILE 1024

// Row-local DPP permute (VALU, ~2-4cyc). ctrl must be a literal.
// 0xB1 = quad_perm [1,0,3,2] = xor1; 0x4E = quad_perm [2,3,0,1] = xor2;
// 0x141 = row_half_mirror = xor7 (within 8); 0x140 = row_mirror = xor15 (within 16).
#define DPPMOV(v, ctrl) \
    ((unsigned)__builtin_amdgcn_update_dpp(0, (int)(v), (ctrl), 0xF, 0xF, true))

// ---------------------------------------------------------------------------
// Kernel 1: router (UNCHANGED from the passing R5 kernel).
// ---------------------------------------------------------------------------
__global__ __launch_bounds__(256, 2) void k_router(
    const float* __restrict__ x,
    const float* __restrict__ rw1, const float* __restrict__ rb1,
    const float* __restrict__ rw2, const float* __restrict__ rb2,
    const float* __restrict__ rw3, const float* __restrict__ rb3,
    float* __restrict__ probs_out, float* __restrict__ unc_out)
{
    __shared__ float XsT[32][68];    // [k][tok]
    __shared__ float WsT[32][132];   // [k][out 0..127]
    __shared__ float H1[64][132];    // [tok][128]
    __shared__ float H2[64][68];     // [tok][64]

    const int tid = threadIdx.x;
    const int tx = tid & 15, ty = tid >> 4;
    const long t0 = (long)blockIdx.x * TOK;

    float acc[4][8];
#pragma unroll
    for (int i = 0; i < 4; i++)
#pragma unroll
        for (int o = 0; o < 8; o++) acc[i][o] = 0.f;

    for (int kc = 0; kc < 16; kc++) {
        __syncthreads();
#pragma unroll
        for (int s = 0; s < 2; s++) {
            int id = tid + s * 256;
            int tok = id >> 3, kq = id & 7;
            float4 v = *(const float4*)&x[(t0 + tok) * 512 + kc * 32 + kq * 4];
            XsT[kq * 4 + 0][tok] = v.x; XsT[kq * 4 + 1][tok] = v.y;
            XsT[kq * 4 + 2][tok] = v.z; XsT[kq * 4 + 3][tok] = v.w;
        }
#pragma unroll
        for (int s = 0; s < 4; s++) {
            int id = tid + s * 256;
            int out = id >> 3, kq = id & 7;
            float4 v = *(const float4*)&rw1[(long)out * 512 + kc * 32 + kq * 4];
            WsT[kq * 4 + 0][out] = v.x; WsT[kq * 4 + 1][out] = v.y;
            WsT[kq * 4 + 2][out] = v.z; WsT[kq * 4 + 3][out] = v.w;
        }
        __syncthreads();
#pragma unroll
        for (int k = 0; k < 32; k++) {
            const float4 xv = *(const float4*)&XsT[k][ty * 4];
            const float4 wa = *(const float4*)&WsT[k][tx * 4];
            const float4 wb = *(const float4*)&WsT[k][64 + tx * 4];
            const float xs[4] = {xv.x, xv.y, xv.z, xv.w};
            const float ws[8] = {wa.x, wa.y, wa.z, wa.w, wb.x, wb.y, wb.z, wb.w};
#pragma unroll
            for (int i = 0; i < 4; i++)
#pragma unroll
                for (int o = 0; o < 8; o++)
                    acc[i][o] = fmaf(xs[i], ws[o], acc[i][o]);
        }
    }

#pragma unroll
    for (int o = 0; o < 8; o++) {
        const int col = (o < 4) ? (tx * 4 + o) : (64 + tx * 4 + (o - 4));
        float b = rb1[col];
#pragma unroll
        for (int i = 0; i < 4; i++) {
            float v = acc[i][o] + b;
            H1[ty * 4 + i][col] = v > 0.f ? v : 0.f;
        }
    }
    __syncthreads();

    float a2[4][4];
#pragma unroll
    for (int i = 0; i < 4; i++)
#pragma unroll
        for (int o = 0; o < 4; o++) a2[i][o] = 0.f;

    for (int k4 = 0; k4 < 32; k4++) {
        float4 hv[4], wv[4];
#pragma unroll
        for (int i = 0; i < 4; i++) hv[i] = *(const float4*)&H1[ty * 4 + i][k4 * 4];
#pragma unroll
        for (int o = 0; o < 4; o++) wv[o] = *(const float4*)&rw2[(tx * 4 + o) * 128 + k4 * 4];
#pragma unroll
        for (int i = 0; i < 4; i++)
#pragma unroll
            for (int o = 0; o < 4; o++)
                a2[i][o] += hv[i].x * wv[o].x + hv[i].y * wv[o].y +
                            hv[i].z * wv[o].z + hv[i].w * wv[o].w;
    }
#pragma unroll
    for (int o = 0; o < 4; o++) {
        float b = rb2[tx * 4 + o];
#pragma unroll
        for (int i = 0; i < 4; i++) {
            float v = a2[i][o] + b;
            H2[ty * 4 + i][tx * 4 + o] = v > 0.f ? v : 0.f;
        }
    }
    __syncthreads();

    if (tid < 64) {
        int tok = tid;
        float lg[4];
#pragma unroll
        for (int r = 0; r < 4; r++) {
            float s = rb3[r];
            for (int k4 = 0; k4 < 16; k4++) {
                float4 h = *(const float4*)&H2[tok][k4 * 4];
                float4 w = *(const float4*)&rw3[r * 64 + k4 * 4];
                s += h.x * w.x + h.y * w.y + h.z * w.z + h.w * w.w;
            }
            lg[r] = s;
        }
        float m = fmaxf(fmaxf(lg[0], lg[1]), fmaxf(lg[2], lg[3]));
        float e0 = __expf(lg[0] - m), e1 = __expf(lg[1] - m);
        float e2 = __expf(lg[2] - m), e3 = __expf(lg[3] - m);
        float inv = __builtin_amdgcn_rcpf(e0 + e1 + e2 + e3);
        float p0 = e0 * inv, p1 = e1 * inv, p2 = e2 * inv, p3 = e3 * inv;
        *(float4*)&probs_out[(t0 + tok) * 4] = make_float4(p0, p1, p2, p3);
        float mean = 0.25f * (p0 + p1 + p2 + p3);
        float d0 = p0 - mean, d1 = p1 - mean, d2 = p2 - mean, d3 = p3 - mean;
        unc_out[t0 + tok] = sqrtf((d0 * d0 + d1 * d1 + d2 * d2 + d3 * d3) * (1.f / 3.f));
    }
}

// ---------------------------------------------------------------------------
// Kernel 2: blocks 0..31 GRU (register-replicated h, VALU-only broadcast);
// blocks 32..1055 experts (UNCHANGED from R5).
//
// GRU layout: lane l: i = l&15, sOwn = (l>>5)&1, j = i | (sOwn<<4).
//   Lanes 0-31 compute j=0..15 (rows 0,1 duplicate), 32-63 j=16..31.
//   Each lane computes the FULL K=32 dot for its j from a replicated h held
//   in 32 regs: hA[p] = h[sOwn*16 + (i^p)] (own slice), hB[p] = other slice.
//   Step-end rebuild: 15 row-local DPP moves (xor tree: values of lanes i^p,
//   p=1..15, within the 16-lane row) + 16 permlane32_swap (rows 0,1 hold
//   slice 0; rows 2,3 slice 1 -> l^32 crosses slices). Swap element order
//   (which of {r0,r1} is the partner) is probed ONCE with lane-id at init.
//   No LDS, no lgkmcnt in the 2048-step recurrence.
// ---------------------------------------------------------------------------
__global__ __launch_bounds__(256, 2) void k_experts_gru(
    const float* __restrict__ x,
    const float* __restrict__ ew1, const float* __restrict__ eb1,
    const float* __restrict__ ew2, const float* __restrict__ eb2,
    const float* __restrict__ probs, float* __restrict__ weighted_out,
    const float* __restrict__ gwih, const float* __restrict__ gwhh,
    const float* __restrict__ gbih, const float* __restrict__ gbhh,
    float* __restrict__ trans_out)
{
    if (blockIdx.x < 32) {
        // ------------------------- GRU path -------------------------
        if (threadIdx.x >= 64) return;
        const int b = blockIdx.x;
        const int l = threadIdx.x;
        const int i = l & 15;
        const int sOwn = (l >> 5) & 1;
        const int j = i | (sOwn << 4);

        // Weights xor-permuted to the tree's register order.
        float wA[3][16], wB[3][16];
#pragma unroll
        for (int g = 0; g < 3; g++) {
            const float* row = gwhh + (j + 32 * g) * 32;
#pragma unroll
            for (int p = 0; p < 16; p++) {
                wA[g][p] = row[sOwn * 16 + (i ^ p)];
                wB[g][p] = row[(1 - sOwn) * 16 + (i ^ p)];
            }
        }
        float wih[3][4];
#pragma unroll
        for (int g = 0; g < 3; g++) {
            float4 w = *(const float4*)&gwih[(j + 32 * g) * 4];
            wih[g][0] = w.x; wih[g][1] = w.y; wih[g][2] = w.z; wih[g][3] = w.w;
        }
        const float bR = gbih[j] + gbhh[j];
        const float bZ = gbih[j + 32] + gbhh[j + 32];
        const float bIN = gbih[j + 64], bHN = gbhh[j + 64];

        // Probe permlane32_swap element order once (per-lane constant).
        unsigned lid = (unsigned)l;
        auto rt = __builtin_amdgcn_permlane32_swap(lid, lid, false, false);
        const bool r0_own = ((unsigned)rt[0] == lid);

        float hA[16], hB[16];
#pragma unroll
        for (int p = 0; p < 16; p++) { hA[p] = 0.f; hB[p] = 0.f; }
        float hj = 0.f;

        const float* pb = probs + (long)b * 2048 * 4;
        float4 p0 = *(const float4*)pb;
        float4 p1 = *(const float4*)(pb + 4);
        float* tr = trans_out + (long)b * 2048 * 32 + j;
        const bool writer = ((l & 16) == 0);

        for (int t = 0; t < 2048; t++) {
            const int tn = (t + 2 < 2048) ? (t + 2) : 2047;
            float4 p2 = *(const float4*)(pb + tn * 4);   // prefetch distance 2

            // full K=32 matvec: 3 gates x (16 own-slice + 16 other-slice)
            float cR0 = 0.f, cR1 = 0.f, cZ0 = 0.f, cZ1 = 0.f, cN0 = 0.f, cN1 = 0.f;
            float dR0 = 0.f, dR1 = 0.f, dZ0 = 0.f, dZ1 = 0.f, dN0 = 0.f, dN1 = 0.f;
#pragma unroll
            for (int p = 0; p < 16; p += 2) {
                cR0 = fmaf(wA[0][p],     hA[p],     cR0);
                cR1 = fmaf(wA[0][p + 1], hA[p + 1], cR1);
                cZ0 = fmaf(wA[1][p],     hA[p],     cZ0);
                cZ1 = fmaf(wA[1][p + 1], hA[p + 1], cZ1);
                cN0 = fmaf(wA[2][p],     hA[p],     cN0);
                cN1 = fmaf(wA[2][p + 1], hA[p + 1], cN1);
                dR0 = fmaf(wB[0][p],     hB[p],     dR0);
                dR1 = fmaf(wB[0][p + 1], hB[p + 1], dR1);
                dZ0 = fmaf(wB[1][p],     hB[p],     dZ0);
                dZ1 = fmaf(wB[1][p + 1], hB[p + 1], dZ1);
                dN0 = fmaf(wB[2][p],     hB[p],     dN0);
                dN1 = fmaf(wB[2][p + 1], hB[p + 1], dN1);
            }
            float dotR = (cR0 + cR1) + (dR0 + dR1);
            float dotZ = (cZ0 + cZ1) + (dZ0 + dZ1);
            float dotN = (cN0 + cN1) + (dN0 + dN1);

            // input-gate dots (independent of h)
            float giR = fmaf(wih[0][3], p0.w, fmaf(wih[0][2], p0.z,
                        fmaf(wih[0][1], p0.y, fmaf(wih[0][0], p0.x, bR))));
            float giZ = fmaf(wih[1][3], p0.w, fmaf(wih[1][2], p0.z,
                        fmaf(wih[1][1], p0.y, fmaf(wih[1][0], p0.x, bZ))));
            float giN = fmaf(wih[2][3], p0.w, fmaf(wih[2][2], p0.z,
                        fmaf(wih[2][1], p0.y, fmaf(wih[2][0], p0.x, bIN))));

            float r = __builtin_amdgcn_rcpf(1.f + __expf(-(giR + dotR)));
            float z = __builtin_amdgcn_rcpf(1.f + __expf(-(giZ + dotZ)));
            float nx = giN + r * (dotN + bHN);
            float n = fmaf(2.f, __builtin_amdgcn_rcpf(1.f + __expf(-2.f * nx)), -1.f);
            hj = fmaf(z, hj - n, n);              // (1-z)*n + z*h

            if (writer) tr[t * 32] = hj;

            // --- rebuild replicated h: 15 DPP (row-local xor tree) ---
            unsigned h0 = __builtin_bit_cast(unsigned, hj);
            unsigned v1  = DPPMOV(h0, 0xB1);   // i^1
            unsigned v2  = DPPMOV(h0, 0x4E);   // i^2
            unsigned v3  = DPPMOV(v1, 0x4E);   // i^3
            unsigned v7  = DPPMOV(h0, 0x141);  // i^7
            unsigned v6  = DPPMOV(v1, 0x141);  // i^6
            unsigned v5  = DPPMOV(v2, 0x141);  // i^5
            unsigned v4  = DPPMOV(v3, 0x141);  // i^4
            unsigned v15 = DPPMOV(h0, 0x140);  // i^15
            unsigned v14 = DPPMOV(v1, 0x140);  // i^14
            unsigned v13 = DPPMOV(v2, 0x140);  // i^13
            unsigned v12 = DPPMOV(v3, 0x140);  // i^12
            unsigned v11 = DPPMOV(v4, 0x140);  // i^11
            unsigned v10 = DPPMOV(v5, 0x140);  // i^10
            unsigned v9  = DPPMOV(v6, 0x140);  // i^9
            unsigned v8  = DPPMOV(v7, 0x140);  // i^8
            unsigned tv[16] = {h0, v1, v2, v3, v4, v5, v6, v7,
                               v8, v9, v10, v11, v12, v13, v14, v15};
            // --- other slice via permlane32_swap (rows 0,1 <-> 2,3) ---
#pragma unroll
            for (int p = 0; p < 16; p++) {
                auto rp = __builtin_amdgcn_permlane32_swap(tv[p], tv[p], false, false);
                unsigned partner = r0_own ? (unsigned)rp[1] : (unsigned)rp[0];
                hA[p] = __builtin_bit_cast(float, tv[p]);
                hB[p] = __builtin_bit_cast(float, partner);
            }

            p0 = p1; p1 = p2;
        }
        return;
    }

    // ------------------------- experts path (R5, unchanged) -------------------------
    __shared__ float XsT[32][68];
    __shared__ float WsT[32][132];
    __shared__ float E1[64][132];
    __shared__ float pS[64][4];

    const int tid = threadIdx.x;
    const int tx = tid & 15, ty = tid >> 4;
    const long t0 = (long)(blockIdx.x - 32) * TOK;

    if (tid < 64) *(float4*)&pS[tid][0] = *(const float4*)&probs[(t0 + tid) * 4];

    float wacc[4][8];
#pragma unroll
    for (int i = 0; i < 4; i++)
#pragma unroll
        for (int o = 0; o < 8; o++) wacc[i][o] = 0.f;

    for (int g = 0; g < 2; g++) {   // regime pairs {0,1}, {2,3}
        float acc[4][8];
#pragma unroll
        for (int i = 0; i < 4; i++)
#pragma unroll
            for (int o = 0; o < 8; o++) acc[i][o] = 0.f;

        for (int kc = 0; kc < 16; kc++) {
            __syncthreads();
#pragma unroll
            for (int s = 0; s < 2; s++) {
                int id = tid + s * 256;
                int tok = id >> 3, kq = id & 7;
                float4 v = *(const float4*)&x[(t0 + tok) * 512 + kc * 32 + kq * 4];
                XsT[kq * 4 + 0][tok] = v.x; XsT[kq * 4 + 1][tok] = v.y;
                XsT[kq * 4 + 2][tok] = v.z; XsT[kq * 4 + 3][tok] = v.w;
            }
#pragma unroll
            for (int s = 0; s < 4; s++) {
                int id = tid + s * 256;
                int out = id >> 3, kq = id & 7;
                float4 v = *(const float4*)&ew1[(long)(g * 128 + out) * 512 + kc * 32 + kq * 4];
                WsT[kq * 4 + 0][out] = v.x; WsT[kq * 4 + 1][out] = v.y;
                WsT[kq * 4 + 2][out] = v.z; WsT[kq * 4 + 3][out] = v.w;
            }
            __syncthreads();
#pragma unroll
            for (int k = 0; k < 32; k++) {
                const float4 xv = *(const float4*)&XsT[k][ty * 4];
                const float4 wa = *(const float4*)&WsT[k][tx * 4];
                const float4 wb = *(const float4*)&WsT[k][64 + tx * 4];
                const float xs[4] = {xv.x, xv.y, xv.z, xv.w};
                const float ws[8] = {wa.x, wa.y, wa.z, wa.w, wb.x, wb.y, wb.z, wb.w};
#pragma unroll
                for (int i = 0; i < 4; i++)
#pragma unroll
                    for (int o = 0; o < 8; o++)
                        acc[i][o] = fmaf(xs[i], ws[o], acc[i][o]);
            }
        }
        __syncthreads();
#pragma unroll
        for (int o = 0; o < 8; o++) {
            const int col = (o < 4) ? (tx * 4 + o) : (64 + tx * 4 + (o - 4));
            float b = eb1[g * 128 + col];
#pragma unroll
            for (int i = 0; i < 4; i++) {
                float v = acc[i][o] + b;
                E1[ty * 4 + i][col] = v > 0.f ? v : 0.f;
            }
        }
        __syncthreads();

        const int rl = tx >> 3;
        const int fb = (tx & 7) * 8;
        const int rg = g * 2 + rl;

        float a2[4][8];
#pragma unroll
        for (int i = 0; i < 4; i++)
#pragma unroll
            for (int o = 0; o < 8; o++) a2[i][o] = 0.f;

        for (int k4 = 0; k4 < 16; k4++) {
            float4 hv[4];
#pragma unroll
            for (int i = 0; i < 4; i++)
                hv[i] = *(const float4*)&E1[ty * 4 + i][rl * 64 + k4 * 4];
#pragma unroll
            for (int o = 0; o < 8; o++) {
                float4 wv = *(const float4*)&ew2[(long)(rg * 64 + fb + o) * 64 + k4 * 4];
#pragma unroll
                for (int i = 0; i < 4; i++)
                    a2[i][o] += hv[i].x * wv.x + hv[i].y * wv.y +
                                hv[i].z * wv.z + hv[i].w * wv.w;
            }
        }
        float pr[4];
#pragma unroll
        for (int i = 0; i < 4; i++) pr[i] = pS[ty * 4 + i][rg];
#pragma unroll
        for (int o = 0; o < 8; o++) {
            float b = eb2[rg * 64 + fb + o];
#pragma unroll
            for (int i = 0; i < 4; i++) {
                float v = a2[i][o] + b;
                v = v > 0.f ? v : 0.f;
                wacc[i][o] = fmaf(pr[i], v, wacc[i][o]);
            }
        }
        __syncthreads();
    }

#pragma unroll
    for (int i = 0; i < 4; i++)
#pragma unroll
        for (int o = 0; o < 8; o++)
            wacc[i][o] += __shfl_xor(wacc[i][o], 8);

    if ((tx & 8) == 0) {
#pragma unroll
        for (int i = 0; i < 4; i++) {
            float4 v0 = make_float4(wacc[i][0], wacc[i][1], wacc[i][2], wacc[i][3]);
            float4 v1 = make_float4(wacc[i][4], wacc[i][5], wacc[i][6], wacc[i][7]);
            long base = (t0 + ty * 4 + i) * 64 + (tx & 7) * 8;
            *(float4*)&weighted_out[base] = v0;
            *(float4*)&weighted_out[base + 4] = v1;
        }
    }
}

extern "C" void kernel_launch(void* const* d_in, const int* in_sizes, int n_in,
                              void* d_out, int out_size, void* d_ws, size_t ws_size,
                              hipStream_t stream) {
    const float* x    = (const float*)d_in[0];
    const float* rw1  = (const float*)d_in[1];
    const float* rb1  = (const float*)d_in[2];
    const float* rw2  = (const float*)d_in[3];
    const float* rb2  = (const float*)d_in[4];
    const float* rw3  = (const float*)d_in[5];
    const float* rb3  = (const float*)d_in[6];
    const float* ew1  = (const float*)d_in[7];
    const float* eb1  = (const float*)d_in[8];
    const float* ew2  = (const float*)d_in[9];
    const float* eb2  = (const float*)d_in[10];
    const float* gwih = (const float*)d_in[11];
    const float* gwhh = (const float*)d_in[12];
    const float* gbih = (const float*)d_in[13];
    const float* gbhh = (const float*)d_in[14];

    float* out        = (float*)d_out;
    float* probs_o    = out;                         // 32*2048*4
    float* weighted_o = out + 262144;                // 32*2048*64
    float* trans_o    = out + 262144 + 4194304;      // 32*2048*32
    float* unc_o      = trans_o + 2097152;           // 32*2048

    hipLaunchKernelGGL(k_router, dim3(NTILE), dim3(256), 0, stream,
                       x, rw1, rb1, rw2, rb2, rw3, rb3, probs_o, unc_o);
    hipLaunchKernelGGL(k_experts_gru, dim3(NTILE + 32), dim3(256), 0, stream,
                       x, ew1, eb1, ew2, eb2, probs_o, weighted_o,
                       gwih, gwhh, gbih, gbhh, trans_o);
}

// Round 9
// 779.439 us; speedup vs baseline: 1.4438x; 1.4438x over previous
//
#include <hip/hip_runtime.h>
#include <math.h>

// B=32, S=2048, D=512, R=4, H=32. Tokens = 65536. Tile = 64 tokens.
#define NTOK 65536
#define TOK 64
#define NTILE 1024

typedef float v2f __attribute__((ext_vector_type(2)));

// Cross-half sum via the gfx950 permlane32_swap BUILTIN (SSA-safe; never the
// inline-asm "+v","+v" form — R4: allocator coalesces identical tied operands
// -> self-swap). r0+r1 == x + shfl_xor(x,32) bit-exactly (fp add commutes).
__device__ __forceinline__ float xhalf_sum(float a) {
    unsigned ai = __builtin_bit_cast(unsigned, a);
    auto r = __builtin_amdgcn_permlane32_swap(ai, ai, false, false);
    return __builtin_bit_cast(float, (unsigned)r[0]) +
           __builtin_bit_cast(float, (unsigned)r[1]);
}

// ---------------------------------------------------------------------------
// Kernel 1: router (UNCHANGED from the passing R5 kernel).
// ---------------------------------------------------------------------------
__global__ __launch_bounds__(256, 2) void k_router(
    const float* __restrict__ x,
    const float* __restrict__ rw1, const float* __restrict__ rb1,
    const float* __restrict__ rw2, const float* __restrict__ rb2,
    const float* __restrict__ rw3, const float* __restrict__ rb3,
    float* __restrict__ probs_out, float* __restrict__ unc_out)
{
    __shared__ float XsT[32][68];    // [k][tok]
    __shared__ float WsT[32][132];   // [k][out 0..127]
    __shared__ float H1[64][132];    // [tok][128]
    __shared__ float H2[64][68];     // [tok][64]

    const int tid = threadIdx.x;
    const int tx = tid & 15, ty = tid >> 4;
    const long t0 = (long)blockIdx.x * TOK;

    float acc[4][8];
#pragma unroll
    for (int i = 0; i < 4; i++)
#pragma unroll
        for (int o = 0; o < 8; o++) acc[i][o] = 0.f;

    for (int kc = 0; kc < 16; kc++) {
        __syncthreads();
#pragma unroll
        for (int s = 0; s < 2; s++) {
            int id = tid + s * 256;
            int tok = id >> 3, kq = id & 7;
            float4 v = *(const float4*)&x[(t0 + tok) * 512 + kc * 32 + kq * 4];
            XsT[kq * 4 + 0][tok] = v.x; XsT[kq * 4 + 1][tok] = v.y;
            XsT[kq * 4 + 2][tok] = v.z; XsT[kq * 4 + 3][tok] = v.w;
        }
#pragma unroll
        for (int s = 0; s < 4; s++) {
            int id = tid + s * 256;
            int out = id >> 3, kq = id & 7;
            float4 v = *(const float4*)&rw1[(long)out * 512 + kc * 32 + kq * 4];
            WsT[kq * 4 + 0][out] = v.x; WsT[kq * 4 + 1][out] = v.y;
            WsT[kq * 4 + 2][out] = v.z; WsT[kq * 4 + 3][out] = v.w;
        }
        __syncthreads();
#pragma unroll
        for (int k = 0; k < 32; k++) {
            const float4 xv = *(const float4*)&XsT[k][ty * 4];
            const float4 wa = *(const float4*)&WsT[k][tx * 4];
            const float4 wb = *(const float4*)&WsT[k][64 + tx * 4];
            const float xs[4] = {xv.x, xv.y, xv.z, xv.w};
            const float ws[8] = {wa.x, wa.y, wa.z, wa.w, wb.x, wb.y, wb.z, wb.w};
#pragma unroll
            for (int i = 0; i < 4; i++)
#pragma unroll
                for (int o = 0; o < 8; o++)
                    acc[i][o] = fmaf(xs[i], ws[o], acc[i][o]);
        }
    }

#pragma unroll
    for (int o = 0; o < 8; o++) {
        const int col = (o < 4) ? (tx * 4 + o) : (64 + tx * 4 + (o - 4));
        float b = rb1[col];
#pragma unroll
        for (int i = 0; i < 4; i++) {
            float v = acc[i][o] + b;
            H1[ty * 4 + i][col] = v > 0.f ? v : 0.f;
        }
    }
    __syncthreads();

    float a2[4][4];
#pragma unroll
    for (int i = 0; i < 4; i++)
#pragma unroll
        for (int o = 0; o < 4; o++) a2[i][o] = 0.f;

    for (int k4 = 0; k4 < 32; k4++) {
        float4 hv[4], wv[4];
#pragma unroll
        for (int i = 0; i < 4; i++) hv[i] = *(const float4*)&H1[ty * 4 + i][k4 * 4];
#pragma unroll
        for (int o = 0; o < 4; o++) wv[o] = *(const float4*)&rw2[(tx * 4 + o) * 128 + k4 * 4];
#pragma unroll
        for (int i = 0; i < 4; i++)
#pragma unroll
            for (int o = 0; o < 4; o++)
                a2[i][o] += hv[i].x * wv[o].x + hv[i].y * wv[o].y +
                            hv[i].z * wv[o].z + hv[i].w * wv[o].w;
    }
#pragma unroll
    for (int o = 0; o < 4; o++) {
        float b = rb2[tx * 4 + o];
#pragma unroll
        for (int i = 0; i < 4; i++) {
            float v = a2[i][o] + b;
            H2[ty * 4 + i][tx * 4 + o] = v > 0.f ? v : 0.f;
        }
    }
    __syncthreads();

    if (tid < 64) {
        int tok = tid;
        float lg[4];
#pragma unroll
        for (int r = 0; r < 4; r++) {
            float s = rb3[r];
            for (int k4 = 0; k4 < 16; k4++) {
                float4 h = *(const float4*)&H2[tok][k4 * 4];
                float4 w = *(const float4*)&rw3[r * 64 + k4 * 4];
                s += h.x * w.x + h.y * w.y + h.z * w.z + h.w * w.w;
            }
            lg[r] = s;
        }
        float m = fmaxf(fmaxf(lg[0], lg[1]), fmaxf(lg[2], lg[3]));
        float e0 = __expf(lg[0] - m), e1 = __expf(lg[1] - m);
        float e2 = __expf(lg[2] - m), e3 = __expf(lg[3] - m);
        float inv = __builtin_amdgcn_rcpf(e0 + e1 + e2 + e3);
        float p0 = e0 * inv, p1 = e1 * inv, p2 = e2 * inv, p3 = e3 * inv;
        *(float4*)&probs_out[(t0 + tok) * 4] = make_float4(p0, p1, p2, p3);
        float mean = 0.25f * (p0 + p1 + p2 + p3);
        float d0 = p0 - mean, d1 = p1 - mean, d2 = p2 - mean, d3 = p3 - mean;
        unc_out[t0 + tok] = sqrtf((d0 * d0 + d1 * d1 + d2 * d2 + d3 * d3) * (1.f / 3.f));
    }
}

// ---------------------------------------------------------------------------
// Kernel 2: blocks 0..31 GRU; blocks 32..1055 experts (UNCHANGED from R5).
//
// GRU: one wave per batch; lane l: j = l&31, half = l>>5. EXACT R5 fp
// accumulation order (recurrence amplifies per-step rounding ~5e3x):
//   - dot: even-k chain (.x) and odd-k chain (.y) as v2f packed FMA
//     (v_pk_fma_f32: per-element IEEE FMA, bit-identical to the two scalar
//     chains, half the issue cycles).
//   - cross-half: xhalf_sum(aX.x + aX.y) — unchanged.
//   - broadcast: 16 __shfl (ds_bpermute register-pull) replaces R5's
//     ds_write + lgkmcnt(0) drain + 4x ds_read_b128. Shfls are mutually
//     independent -> pipeline to ~one DS latency; no LDS storage at all.
// ---------------------------------------------------------------------------
__global__ __launch_bounds__(256, 2) void k_experts_gru(
    const float* __restrict__ x,
    const float* __restrict__ ew1, const float* __restrict__ eb1,
    const float* __restrict__ ew2, const float* __restrict__ eb2,
    const float* __restrict__ probs, float* __restrict__ weighted_out,
    const float* __restrict__ gwih, const float* __restrict__ gwhh,
    const float* __restrict__ gbih, const float* __restrict__ gbhh,
    float* __restrict__ trans_out)
{
    if (blockIdx.x < 32) {
        // ------------------------- GRU path -------------------------
        if (threadIdx.x >= 64) return;
        const int b = blockIdx.x;
        const int l = threadIdx.x;
        const int j = l & 31, half = l >> 5;
        const int kbase = half * 16;

        // packed W_hh for this lane's K-half: wpk[g][q] = {w[2q], w[2q+1]}
        v2f wpk[3][8];
#pragma unroll
        for (int g = 0; g < 3; g++) {
            const float* wp = gwhh + (j + 32 * g) * 32 + kbase;
#pragma unroll
            for (int q = 0; q < 8; q++) {
                v2f w; w.x = wp[2 * q]; w.y = wp[2 * q + 1];
                wpk[g][q] = w;
            }
        }
        float wih[3][4];
#pragma unroll
        for (int g = 0; g < 3; g++) {
            float4 w = *(const float4*)&gwih[(j + 32 * g) * 4];
            wih[g][0] = w.x; wih[g][1] = w.y; wih[g][2] = w.z; wih[g][3] = w.w;
        }
        const float bR = gbih[j] + gbhh[j];
        const float bZ = gbih[j + 32] + gbhh[j + 32];
        const float bIN = gbih[j + 64], bHN = gbhh[j + 64];

        const float* pb = probs + (long)b * 2048 * 4;
        float4 p0 = *(const float4*)pb;
        float4 p1 = *(const float4*)(pb + 4);
        v2f hpk[8];
#pragma unroll
        for (int q = 0; q < 8; q++) { hpk[q].x = 0.f; hpk[q].y = 0.f; }
        float hj = 0.f;
        float* tr = trans_out + (long)b * 2048 * 32 + j;

        for (int t = 0; t < 2048; t++) {
            const int tn = (t + 2 < 2048) ? (t + 2) : 2047;
            float4 p2 = *(const float4*)(pb + tn * 4);     // prefetch distance 2

            // packed partial matvec (24 pk_fma == R5's 48 scalar fma chains)
            v2f aR; aR.x = 0.f; aR.y = 0.f;
            v2f aZ = aR, aN = aR;
#pragma unroll
            for (int q = 0; q < 8; q++) {
                aR = __builtin_elementwise_fma(wpk[0][q], hpk[q], aR);
                aZ = __builtin_elementwise_fma(wpk[1][q], hpk[q], aZ);
                aN = __builtin_elementwise_fma(wpk[2][q], hpk[q], aN);
            }
            float sR = xhalf_sum(aR.x + aR.y);   // == (aR0+aR1) + shfl_xor(..,32)
            float sZ = xhalf_sum(aZ.x + aZ.y);
            float sN = xhalf_sum(aN.x + aN.y);

            // input-gate dots (independent of h -> overlaps swap latency)
            float giR = fmaf(wih[0][3], p0.w, fmaf(wih[0][2], p0.z,
                        fmaf(wih[0][1], p0.y, fmaf(wih[0][0], p0.x, bR))));
            float giZ = fmaf(wih[1][3], p0.w, fmaf(wih[1][2], p0.z,
                        fmaf(wih[1][1], p0.y, fmaf(wih[1][0], p0.x, bZ))));
            float giN = fmaf(wih[2][3], p0.w, fmaf(wih[2][2], p0.z,
                        fmaf(wih[2][1], p0.y, fmaf(wih[2][0], p0.x, bIN))));

            float r = __builtin_amdgcn_rcpf(1.f + __expf(-(giR + sR)));
            float z = __builtin_amdgcn_rcpf(1.f + __expf(-(giZ + sZ)));
            float nx = giN + r * (sN + bHN);
            float n = fmaf(2.f, __builtin_amdgcn_rcpf(1.f + __expf(-2.f * nx)), -1.f);
            hj = fmaf(z, hj - n, n);              // (1-z)*n + z*h

            if (l < 32) tr[t * 32] = hj;

            // broadcast rebuild: 16 independent register-pulls (ds_bpermute)
#pragma unroll
            for (int q = 0; q < 8; q++) {
                hpk[q].x = __shfl(hj, kbase + 2 * q);
                hpk[q].y = __shfl(hj, kbase + 2 * q + 1);
            }
            p0 = p1; p1 = p2;
        }
        return;
    }

    // ------------------------- experts path (R5, unchanged) -------------------------
    __shared__ float XsT[32][68];
    __shared__ float WsT[32][132];
    __shared__ float E1[64][132];
    __shared__ float pS[64][4];

    const int tid = threadIdx.x;
    const int tx = tid & 15, ty = tid >> 4;
    const long t0 = (long)(blockIdx.x - 32) * TOK;

    if (tid < 64) *(float4*)&pS[tid][0] = *(const float4*)&probs[(t0 + tid) * 4];

    float wacc[4][8];
#pragma unroll
    for (int i = 0; i < 4; i++)
#pragma unroll
        for (int o = 0; o < 8; o++) wacc[i][o] = 0.f;

    for (int g = 0; g < 2; g++) {   // regime pairs {0,1}, {2,3}
        float acc[4][8];
#pragma unroll
        for (int i = 0; i < 4; i++)
#pragma unroll
            for (int o = 0; o < 8; o++) acc[i][o] = 0.f;

        for (int kc = 0; kc < 16; kc++) {
            __syncthreads();
#pragma unroll
            for (int s = 0; s < 2; s++) {
                int id = tid + s * 256;
                int tok = id >> 3, kq = id & 7;
                float4 v = *(const float4*)&x[(t0 + tok) * 512 + kc * 32 + kq * 4];
                XsT[kq * 4 + 0][tok] = v.x; XsT[kq * 4 + 1][tok] = v.y;
                XsT[kq * 4 + 2][tok] = v.z; XsT[kq * 4 + 3][tok] = v.w;
            }
#pragma unroll
            for (int s = 0; s < 4; s++) {
                int id = tid + s * 256;
                int out = id >> 3, kq = id & 7;
                float4 v = *(const float4*)&ew1[(long)(g * 128 + out) * 512 + kc * 32 + kq * 4];
                WsT[kq * 4 + 0][out] = v.x; WsT[kq * 4 + 1][out] = v.y;
                WsT[kq * 4 + 2][out] = v.z; WsT[kq * 4 + 3][out] = v.w;
            }
            __syncthreads();
#pragma unroll
            for (int k = 0; k < 32; k++) {
                const float4 xv = *(const float4*)&XsT[k][ty * 4];
                const float4 wa = *(const float4*)&WsT[k][tx * 4];
                const float4 wb = *(const float4*)&WsT[k][64 + tx * 4];
                const float xs[4] = {xv.x, xv.y, xv.z, xv.w};
                const float ws[8] = {wa.x, wa.y, wa.z, wa.w, wb.x, wb.y, wb.z, wb.w};
#pragma unroll
                for (int i = 0; i < 4; i++)
#pragma unroll
                    for (int o = 0; o < 8; o++)
                        acc[i][o] = fmaf(xs[i], ws[o], acc[i][o]);
            }
        }
        __syncthreads();
#pragma unroll
        for (int o = 0; o < 8; o++) {
            const int col = (o < 4) ? (tx * 4 + o) : (64 + tx * 4 + (o - 4));
            float b = eb1[g * 128 + col];
#pragma unroll
            for (int i = 0; i < 4; i++) {
                float v = acc[i][o] + b;
                E1[ty * 4 + i][col] = v > 0.f ? v : 0.f;
            }
        }
        __syncthreads();

        const int rl = tx >> 3;
        const int fb = (tx & 7) * 8;
        const int rg = g * 2 + rl;

        float a2[4][8];
#pragma unroll
        for (int i = 0; i < 4; i++)
#pragma unroll
            for (int o = 0; o < 8; o++) a2[i][o] = 0.f;

        for (int k4 = 0; k4 < 16; k4++) {
            float4 hv[4];
#pragma unroll
            for (int i = 0; i < 4; i++)
                hv[i] = *(const float4*)&E1[ty * 4 + i][rl * 64 + k4 * 4];
#pragma unroll
            for (int o = 0; o < 8; o++) {
                float4 wv = *(const float4*)&ew2[(long)(rg * 64 + fb + o) * 64 + k4 * 4];
#pragma unroll
                for (int i = 0; i < 4; i++)
                    a2[i][o] += hv[i].x * wv.x + hv[i].y * wv.y +
                                hv[i].z * wv.z + hv[i].w * wv.w;
            }
        }
        float pr[4];
#pragma unroll
        for (int i = 0; i < 4; i++) pr[i] = pS[ty * 4 + i][rg];
#pragma unroll
        for (int o = 0; o < 8; o++) {
            float b = eb2[rg * 64 + fb + o];
#pragma unroll
            for (int i = 0; i < 4; i++) {
                float v = a2[i][o] + b;
                v = v > 0.f ? v : 0.f;
                wacc[i][o] = fmaf(pr[i], v, wacc[i][o]);
            }
        }
        __syncthreads();
    }

#pragma unroll
    for (int i = 0; i < 4; i++)
#pragma unroll
        for (int o = 0; o < 8; o++)
            wacc[i][o] += __shfl_xor(wacc[i][o], 8);

    if ((tx & 8) == 0) {
#pragma unroll
        for (int i = 0; i < 4; i++) {
            float4 v0 = make_float4(wacc[i][0], wacc[i][1], wacc[i][2], wacc[i][3]);
            float4 v1 = make_float4(wacc[i][4], wacc[i][5], wacc[i][6], wacc[i][7]);
            long base = (t0 + ty * 4 + i) * 64 + (tx & 7) * 8;
            *(float4*)&weighted_out[base] = v0;
            *(float4*)&weighted_out[base + 4] = v1;
        }
    }
}

extern "C" void kernel_launch(void* const* d_in, const int* in_sizes, int n_in,
                              void* d_out, int out_size, void* d_ws, size_t ws_size,
                              hipStream_t stream) {
    const float* x    = (const float*)d_in[0];
    const float* rw1  = (const float*)d_in[1];
    const float* rb1  = (const float*)d_in[2];
    const float* rw2  = (const float*)d_in[3];
    const float* rb2  = (const float*)d_in[4];
    const float* rw3  = (const float*)d_in[5];
    const float* rb3  = (const float*)d_in[6];
    const float* ew1  = (const float*)d_in[7];
    const float* eb1  = (const float*)d_in[8];
    const float* ew2  = (const float*)d_in[9];
    const float* eb2  = (const float*)d_in[10];
    const float* gwih = (const float*)d_in[11];
    const float* gwhh = (const float*)d_in[12];
    const float* gbih = (const float*)d_in[13];
    const float* gbhh = (const float*)d_in[14];

    float* out        = (float*)d_out;
    float* probs_o    = out;                         // 32*2048*4
    float* weighted_o = out + 262144;                // 32*2048*64
    float* trans_o    = out + 262144 + 4194304;      // 32*2048*32
    float* unc_o      = trans_o + 2097152;           // 32*2048

    hipLaunchKernelGGL(k_router, dim3(NTILE), dim3(256), 0, stream,
                       x, rw1, rb1, rw2, rb2, rw3, rb3, probs_o, unc_o);
    hipLaunchKernelGGL(k_experts_gru, dim3(NTILE + 32), dim3(256), 0, stream,
                       x, ew1, eb1, ew2, eb2, probs_o, weighted_o,
                       gwih, gwhh, gbih, gbhh, trans_o);
}

// Round 10
// 736.942 us; speedup vs baseline: 1.5270x; 1.0577x over previous
//
#include <hip/hip_runtime.h>
#include <math.h>

// B=32, S=2048, D=512, R=4, H=32. Tokens = 65536. Tile = 64 tokens.
#define NTOK 65536
#define TOK 64
#define NTILE 1024

typedef float v2f __attribute__((ext_vector_type(2)));

// Cross-half sum via the gfx950 permlane32_swap BUILTIN (SSA-safe; never the
// inline-asm "+v","+v" form — R4: allocator coalesces identical tied operands
// -> self-swap). r0+r1 == x + shfl_xor(x,32) bit-exactly (fp add commutes).
__device__ __forceinline__ float xhalf_sum(float a) {
    unsigned ai = __builtin_bit_cast(unsigned, a);
    auto r = __builtin_amdgcn_permlane32_swap(ai, ai, false, false);
    return __builtin_bit_cast(float, (unsigned)r[0]) +
           __builtin_bit_cast(float, (unsigned)r[1]);
}

// ---------------------------------------------------------------------------
// Kernel 1: router (UNCHANGED from the passing R5 kernel).
// ---------------------------------------------------------------------------
__global__ __launch_bounds__(256, 2) void k_router(
    const float* __restrict__ x,
    const float* __restrict__ rw1, const float* __restrict__ rb1,
    const float* __restrict__ rw2, const float* __restrict__ rb2,
    const float* __restrict__ rw3, const float* __restrict__ rb3,
    float* __restrict__ probs_out, float* __restrict__ unc_out)
{
    __shared__ float XsT[32][68];    // [k][tok]
    __shared__ float WsT[32][132];   // [k][out 0..127]
    __shared__ float H1[64][132];    // [tok][128]
    __shared__ float H2[64][68];     // [tok][64]

    const int tid = threadIdx.x;
    const int tx = tid & 15, ty = tid >> 4;
    const long t0 = (long)blockIdx.x * TOK;

    float acc[4][8];
#pragma unroll
    for (int i = 0; i < 4; i++)
#pragma unroll
        for (int o = 0; o < 8; o++) acc[i][o] = 0.f;

    for (int kc = 0; kc < 16; kc++) {
        __syncthreads();
#pragma unroll
        for (int s = 0; s < 2; s++) {
            int id = tid + s * 256;
            int tok = id >> 3, kq = id & 7;
            float4 v = *(const float4*)&x[(t0 + tok) * 512 + kc * 32 + kq * 4];
            XsT[kq * 4 + 0][tok] = v.x; XsT[kq * 4 + 1][tok] = v.y;
            XsT[kq * 4 + 2][tok] = v.z; XsT[kq * 4 + 3][tok] = v.w;
        }
#pragma unroll
        for (int s = 0; s < 4; s++) {
            int id = tid + s * 256;
            int out = id >> 3, kq = id & 7;
            float4 v = *(const float4*)&rw1[(long)out * 512 + kc * 32 + kq * 4];
            WsT[kq * 4 + 0][out] = v.x; WsT[kq * 4 + 1][out] = v.y;
            WsT[kq * 4 + 2][out] = v.z; WsT[kq * 4 + 3][out] = v.w;
        }
        __syncthreads();
#pragma unroll
        for (int k = 0; k < 32; k++) {
            const float4 xv = *(const float4*)&XsT[k][ty * 4];
            const float4 wa = *(const float4*)&WsT[k][tx * 4];
            const float4 wb = *(const float4*)&WsT[k][64 + tx * 4];
            const float xs[4] = {xv.x, xv.y, xv.z, xv.w};
            const float ws[8] = {wa.x, wa.y, wa.z, wa.w, wb.x, wb.y, wb.z, wb.w};
#pragma unroll
            for (int i = 0; i < 4; i++)
#pragma unroll
                for (int o = 0; o < 8; o++)
                    acc[i][o] = fmaf(xs[i], ws[o], acc[i][o]);
        }
    }

#pragma unroll
    for (int o = 0; o < 8; o++) {
        const int col = (o < 4) ? (tx * 4 + o) : (64 + tx * 4 + (o - 4));
        float b = rb1[col];
#pragma unroll
        for (int i = 0; i < 4; i++) {
            float v = acc[i][o] + b;
            H1[ty * 4 + i][col] = v > 0.f ? v : 0.f;
        }
    }
    __syncthreads();

    float a2[4][4];
#pragma unroll
    for (int i = 0; i < 4; i++)
#pragma unroll
        for (int o = 0; o < 4; o++) a2[i][o] = 0.f;

    for (int k4 = 0; k4 < 32; k4++) {
        float4 hv[4], wv[4];
#pragma unroll
        for (int i = 0; i < 4; i++) hv[i] = *(const float4*)&H1[ty * 4 + i][k4 * 4];
#pragma unroll
        for (int o = 0; o < 4; o++) wv[o] = *(const float4*)&rw2[(tx * 4 + o) * 128 + k4 * 4];
#pragma unroll
        for (int i = 0; i < 4; i++)
#pragma unroll
            for (int o = 0; o < 4; o++)
                a2[i][o] += hv[i].x * wv[o].x + hv[i].y * wv[o].y +
                            hv[i].z * wv[o].z + hv[i].w * wv[o].w;
    }
#pragma unroll
    for (int o = 0; o < 4; o++) {
        float b = rb2[tx * 4 + o];
#pragma unroll
        for (int i = 0; i < 4; i++) {
            float v = a2[i][o] + b;
            H2[ty * 4 + i][tx * 4 + o] = v > 0.f ? v : 0.f;
        }
    }
    __syncthreads();

    if (tid < 64) {
        int tok = tid;
        float lg[4];
#pragma unroll
        for (int r = 0; r < 4; r++) {
            float s = rb3[r];
            for (int k4 = 0; k4 < 16; k4++) {
                float4 h = *(const float4*)&H2[tok][k4 * 4];
                float4 w = *(const float4*)&rw3[r * 64 + k4 * 4];
                s += h.x * w.x + h.y * w.y + h.z * w.z + h.w * w.w;
            }
            lg[r] = s;
        }
        float m = fmaxf(fmaxf(lg[0], lg[1]), fmaxf(lg[2], lg[3]));
        float e0 = __expf(lg[0] - m), e1 = __expf(lg[1] - m);
        float e2 = __expf(lg[2] - m), e3 = __expf(lg[3] - m);
        float inv = __builtin_amdgcn_rcpf(e0 + e1 + e2 + e3);
        float p0 = e0 * inv, p1 = e1 * inv, p2 = e2 * inv, p3 = e3 * inv;
        *(float4*)&probs_out[(t0 + tok) * 4] = make_float4(p0, p1, p2, p3);
        float mean = 0.25f * (p0 + p1 + p2 + p3);
        float d0 = p0 - mean, d1 = p1 - mean, d2 = p2 - mean, d3 = p3 - mean;
        unc_out[t0 + tok] = sqrtf((d0 * d0 + d1 * d1 + d2 * d2 + d3 * d3) * (1.f / 3.f));
    }
}

// ---------------------------------------------------------------------------
// Kernel 2: blocks 0..31 GRU; blocks 32..1055 experts (UNCHANGED from R5).
//
// GRU: one wave per batch; lane l: j = l&31, half = l>>5. R9 math order
// exactly (bit-identical). New in R10: the probs loads are software-pipelined
// 8 steps deep (t-loop unrolled x4, loads issued 2 groups ahead, all static
// register indices) — R9's distance-2 prefetch forced a vmcnt wait with only
// ~1 step of slack, eating the cross-XCD L2-miss latency (~400cyc) EVERY step.
// ---------------------------------------------------------------------------
__global__ __launch_bounds__(256, 2) void k_experts_gru(
    const float* __restrict__ x,
    const float* __restrict__ ew1, const float* __restrict__ eb1,
    const float* __restrict__ ew2, const float* __restrict__ eb2,
    const float* __restrict__ probs, float* __restrict__ weighted_out,
    const float* __restrict__ gwih, const float* __restrict__ gwhh,
    const float* __restrict__ gbih, const float* __restrict__ gbhh,
    float* __restrict__ trans_out)
{
    if (blockIdx.x < 32) {
        // ------------------------- GRU path -------------------------
        if (threadIdx.x >= 64) return;
        const int b = blockIdx.x;
        const int l = threadIdx.x;
        const int j = l & 31, half = l >> 5;
        const int kbase = half * 16;

        // packed W_hh for this lane's K-half: wpk[g][q] = {w[2q], w[2q+1]}
        v2f wpk[3][8];
#pragma unroll
        for (int g = 0; g < 3; g++) {
            const float* wp = gwhh + (j + 32 * g) * 32 + kbase;
#pragma unroll
            for (int q = 0; q < 8; q++) {
                v2f w; w.x = wp[2 * q]; w.y = wp[2 * q + 1];
                wpk[g][q] = w;
            }
        }
        float wih[3][4];
#pragma unroll
        for (int g = 0; g < 3; g++) {
            float4 w = *(const float4*)&gwih[(j + 32 * g) * 4];
            wih[g][0] = w.x; wih[g][1] = w.y; wih[g][2] = w.z; wih[g][3] = w.w;
        }
        const float bR = gbih[j] + gbhh[j];
        const float bZ = gbih[j + 32] + gbhh[j + 32];
        const float bIN = gbih[j + 64], bHN = gbhh[j + 64];

        const float* pb = probs + (long)b * 2048 * 4;
        v2f hpk[8];
#pragma unroll
        for (int q = 0; q < 8; q++) { hpk[q].x = 0.f; hpk[q].y = 0.f; }
        float hj = 0.f;
        float* tr = trans_out + (long)b * 2048 * 32 + j;

        // software pipeline: groups of 4 steps; loads issued 2 groups ahead.
        float4 pc[4], pn[4];
#pragma unroll
        for (int i = 0; i < 4; i++) {
            pc[i] = *(const float4*)(pb + i * 4);          // t = 0..3
            pn[i] = *(const float4*)(pb + (4 + i) * 4);    // t = 4..7
        }

        for (int tg = 0; tg < 2048; tg += 4) {
            // issue loads for tg+8 .. tg+11 (clamped; dead past the end)
            const int fb0 = (tg + 8  < 2048) ? (tg + 8)  : 2047;
            const int fb1 = (tg + 9  < 2048) ? (tg + 9)  : 2047;
            const int fb2 = (tg + 10 < 2048) ? (tg + 10) : 2047;
            const int fb3 = (tg + 11 < 2048) ? (tg + 11) : 2047;
            float4 pf0 = *(const float4*)(pb + fb0 * 4);
            float4 pf1 = *(const float4*)(pb + fb1 * 4);
            float4 pf2 = *(const float4*)(pb + fb2 * 4);
            float4 pf3 = *(const float4*)(pb + fb3 * 4);

#pragma unroll
            for (int s = 0; s < 4; s++) {
                const float4 p0 = pc[s];

                // packed partial matvec (24 pk_fma == 48 scalar fma chains)
                v2f aR; aR.x = 0.f; aR.y = 0.f;
                v2f aZ = aR, aN = aR;
#pragma unroll
                for (int q = 0; q < 8; q++) {
                    aR = __builtin_elementwise_fma(wpk[0][q], hpk[q], aR);
                    aZ = __builtin_elementwise_fma(wpk[1][q], hpk[q], aZ);
                    aN = __builtin_elementwise_fma(wpk[2][q], hpk[q], aN);
                }
                float sR = xhalf_sum(aR.x + aR.y);
                float sZ = xhalf_sum(aZ.x + aZ.y);
                float sN = xhalf_sum(aN.x + aN.y);

                // input-gate dots (independent of h -> overlap swap latency)
                float giR = fmaf(wih[0][3], p0.w, fmaf(wih[0][2], p0.z,
                            fmaf(wih[0][1], p0.y, fmaf(wih[0][0], p0.x, bR))));
                float giZ = fmaf(wih[1][3], p0.w, fmaf(wih[1][2], p0.z,
                            fmaf(wih[1][1], p0.y, fmaf(wih[1][0], p0.x, bZ))));
                float giN = fmaf(wih[2][3], p0.w, fmaf(wih[2][2], p0.z,
                            fmaf(wih[2][1], p0.y, fmaf(wih[2][0], p0.x, bIN))));

                float r = __builtin_amdgcn_rcpf(1.f + __expf(-(giR + sR)));
                float z = __builtin_amdgcn_rcpf(1.f + __expf(-(giZ + sZ)));
                float nx = giN + r * (sN + bHN);
                float n = fmaf(2.f, __builtin_amdgcn_rcpf(1.f + __expf(-2.f * nx)), -1.f);
                hj = fmaf(z, hj - n, n);              // (1-z)*n + z*h

                if (l < 32) tr[(tg + s) * 32] = hj;

                // broadcast rebuild: 16 independent register-pulls
#pragma unroll
                for (int q = 0; q < 8; q++) {
                    hpk[q].x = __shfl(hj, kbase + 2 * q);
                    hpk[q].y = __shfl(hj, kbase + 2 * q + 1);
                }
            }

            // rotate pipeline (static register moves)
            pc[0] = pn[0]; pc[1] = pn[1]; pc[2] = pn[2]; pc[3] = pn[3];
            pn[0] = pf0;   pn[1] = pf1;   pn[2] = pf2;   pn[3] = pf3;
        }
        return;
    }

    // ------------------------- experts path (R5, unchanged) -------------------------
    __shared__ float XsT[32][68];
    __shared__ float WsT[32][132];
    __shared__ float E1[64][132];
    __shared__ float pS[64][4];

    const int tid = threadIdx.x;
    const int tx = tid & 15, ty = tid >> 4;
    const long t0 = (long)(blockIdx.x - 32) * TOK;

    if (tid < 64) *(float4*)&pS[tid][0] = *(const float4*)&probs[(t0 + tid) * 4];

    float wacc[4][8];
#pragma unroll
    for (int i = 0; i < 4; i++)
#pragma unroll
        for (int o = 0; o < 8; o++) wacc[i][o] = 0.f;

    for (int g = 0; g < 2; g++) {   // regime pairs {0,1}, {2,3}
        float acc[4][8];
#pragma unroll
        for (int i = 0; i < 4; i++)
#pragma unroll
            for (int o = 0; o < 8; o++) acc[i][o] = 0.f;

        for (int kc = 0; kc < 16; kc++) {
            __syncthreads();
#pragma unroll
            for (int s = 0; s < 2; s++) {
                int id = tid + s * 256;
                int tok = id >> 3, kq = id & 7;
                float4 v = *(const float4*)&x[(t0 + tok) * 512 + kc * 32 + kq * 4];
                XsT[kq * 4 + 0][tok] = v.x; XsT[kq * 4 + 1][tok] = v.y;
                XsT[kq * 4 + 2][tok] = v.z; XsT[kq * 4 + 3][tok] = v.w;
            }
#pragma unroll
            for (int s = 0; s < 4; s++) {
                int id = tid + s * 256;
                int out = id >> 3, kq = id & 7;
                float4 v = *(const float4*)&ew1[(long)(g * 128 + out) * 512 + kc * 32 + kq * 4];
                WsT[kq * 4 + 0][out] = v.x; WsT[kq * 4 + 1][out] = v.y;
                WsT[kq * 4 + 2][out] = v.z; WsT[kq * 4 + 3][out] = v.w;
            }
            __syncthreads();
#pragma unroll
            for (int k = 0; k < 32; k++) {
                const float4 xv = *(const float4*)&XsT[k][ty * 4];
                const float4 wa = *(const float4*)&WsT[k][tx * 4];
                const float4 wb = *(const float4*)&WsT[k][64 + tx * 4];
                const float xs[4] = {xv.x, xv.y, xv.z, xv.w};
                const float ws[8] = {wa.x, wa.y, wa.z, wa.w, wb.x, wb.y, wb.z, wb.w};
#pragma unroll
                for (int i = 0; i < 4; i++)
#pragma unroll
                    for (int o = 0; o < 8; o++)
                        acc[i][o] = fmaf(xs[i], ws[o], acc[i][o]);
            }
        }
        __syncthreads();
#pragma unroll
        for (int o = 0; o < 8; o++) {
            const int col = (o < 4) ? (tx * 4 + o) : (64 + tx * 4 + (o - 4));
            float b = eb1[g * 128 + col];
#pragma unroll
            for (int i = 0; i < 4; i++) {
                float v = acc[i][o] + b;
                E1[ty * 4 + i][col] = v > 0.f ? v : 0.f;
            }
        }
        __syncthreads();

        const int rl = tx >> 3;
        const int fb = (tx & 7) * 8;
        const int rg = g * 2 + rl;

        float a2[4][8];
#pragma unroll
        for (int i = 0; i < 4; i++)
#pragma unroll
            for (int o = 0; o < 8; o++) a2[i][o] = 0.f;

        for (int k4 = 0; k4 < 16; k4++) {
            float4 hv[4];
#pragma unroll
            for (int i = 0; i < 4; i++)
                hv[i] = *(const float4*)&E1[ty * 4 + i][rl * 64 + k4 * 4];
#pragma unroll
            for (int o = 0; o < 8; o++) {
                float4 wv = *(const float4*)&ew2[(long)(rg * 64 + fb + o) * 64 + k4 * 4];
#pragma unroll
                for (int i = 0; i < 4; i++)
                    a2[i][o] += hv[i].x * wv.x + hv[i].y * wv.y +
                                hv[i].z * wv.z + hv[i].w * wv.w;
            }
        }
        float pr[4];
#pragma unroll
        for (int i = 0; i < 4; i++) pr[i] = pS[ty * 4 + i][rg];
#pragma unroll
        for (int o = 0; o < 8; o++) {
            float b = eb2[rg * 64 + fb + o];
#pragma unroll
            for (int i = 0; i < 4; i++) {
                float v = a2[i][o] + b;
                v = v > 0.f ? v : 0.f;
                wacc[i][o] = fmaf(pr[i], v, wacc[i][o]);
            }
        }
        __syncthreads();
    }

#pragma unroll
    for (int i = 0; i < 4; i++)
#pragma unroll
        for (int o = 0; o < 8; o++)
            wacc[i][o] += __shfl_xor(wacc[i][o], 8);

    if ((tx & 8) == 0) {
#pragma unroll
        for (int i = 0; i < 4; i++) {
            float4 v0 = make_float4(wacc[i][0], wacc[i][1], wacc[i][2], wacc[i][3]);
            float4 v1 = make_float4(wacc[i][4], wacc[i][5], wacc[i][6], wacc[i][7]);
            long base = (t0 + ty * 4 + i) * 64 + (tx & 7) * 8;
            *(float4*)&weighted_out[base] = v0;
            *(float4*)&weighted_out[base + 4] = v1;
        }
    }
}

extern "C" void kernel_launch(void* const* d_in, const int* in_sizes, int n_in,
                              void* d_out, int out_size, void* d_ws, size_t ws_size,
                              hipStream_t stream) {
    const float* x    = (const float*)d_in[0];
    const float* rw1  = (const float*)d_in[1];
    const float* rb1  = (const float*)d_in[2];
    const float* rw2  = (const float*)d_in[3];
    const float* rb2  = (const float*)d_in[4];
    const float* rw3  = (const float*)d_in[5];
    const float* rb3  = (const float*)d_in[6];
    const float* ew1  = (const float*)d_in[7];
    const float* eb1  = (const float*)d_in[8];
    const float* ew2  = (const float*)d_in[9];
    const float* eb2  = (const float*)d_in[10];
    const float* gwih = (const float*)d_in[11];
    const float* gwhh = (const float*)d_in[12];
    const float* gbih = (const float*)d_in[13];
    const float* gbhh = (const float*)d_in[14];

    float* out        = (float*)d_out;
    float* probs_o    = out;                         // 32*2048*4
    float* weighted_o = out + 262144;                // 32*2048*64
    float* trans_o    = out + 262144 + 4194304;      // 32*2048*32
    float* unc_o      = trans_o + 2097152;           // 32*2048

    hipLaunchKernelGGL(k_router, dim3(NTILE), dim3(256), 0, stream,
                       x, rw1, rb1, rw2, rb2, rw3, rb3, probs_o, unc_o);
    hipLaunchKernelGGL(k_experts_gru, dim3(NTILE + 32), dim3(256), 0, stream,
                       x, ew1, eb1, ew2, eb2, probs_o, weighted_o,
                       gwih, gwhh, gbih, gbhh, trans_o);
}